// Round 1
// 355.632 us; speedup vs baseline: 1.0274x; 1.0274x over previous
//
#include <hip/hip_runtime.h>

// LambdaReturn: reverse-time linear recurrence, T=1000, B=32768, fp32.
//   delta_t = r_t + g*(1-l)*m_t*v_t ;  ret_t = delta_t + g*l*m_t*carry
// One thread per column (512 wave64 blocks = 2 waves/CU). Latency-bound:
// R1 showed VGPR=68 -> the 2x(3x20) register pipeline was collapsed by the
// allocator (default launch_bounds occupancy target), leaving ~4 loads in
// flight (1.44 TB/s cold / 5.2 TB/s L3-warm, matching 365/100 us).
// Fix: __launch_bounds__(64,1) lifts the VGPR budget to 512 so the buffers
// materialize; sched_barrier(0) pins load-issue points (waitcnts still land
// at first use); U=10 keeps the two in-flight groups at 60 loads <= vmcnt
// cap of 63. Target: 60 loads * 256 B = 15 KB in flight/wave, 30 KB/CU vs
// 9.2 KB needed for 6.3 TB/s at ~900 cyc HBM latency.

#define T_DIM 1000
#define B_DIM 32768
#define U 10          // timesteps per group; 1000 = 100 * 10
#define NGROUPS 100

__global__ __launch_bounds__(64, 1) void LambdaReturn_kernel(
    const float* __restrict__ rewards,
    const float* __restrict__ values,
    const float* __restrict__ masks,
    float* __restrict__ out) {
  const int b = blockIdx.x * blockDim.x + threadIdx.x;
  const float c_delta = 0.99f * (1.0f - 0.95f);  // gamma*(1-lambda)
  const float gl      = 0.99f * 0.95f;           // gamma*lambda

  const float* pr = rewards + b;
  const float* pv = values + b;
  const float* pm = masks + b;
  float* po = out + b;

  float carry = pv[(size_t)(T_DIM - 1) * B_DIM];

  float rA[U], vA[U], mA[U];
  float rB[U], vB[U], mB[U];

  // group g covers t = (999 - U*g) down to (999 - U*g - (U-1)), j = 0..U-1
  auto ld = [&](float* r, float* v, float* m, int g) {
    const size_t base = (size_t)(T_DIM - 1 - U * g) * B_DIM;
    #pragma unroll
    for (int j = 0; j < U; ++j) {
      const size_t idx = base - (size_t)j * B_DIM;
      r[j] = __builtin_nontemporal_load(pr + idx);
      v[j] = __builtin_nontemporal_load(pv + idx);
      m[j] = __builtin_nontemporal_load(pm + idx);
    }
    // Pin the issue point: scheduler may not sink these loads past here.
    // Waitcnt insertion is a later pass and still waits only at first use.
    __builtin_amdgcn_sched_barrier(0);
  };
  auto cmp = [&](const float* r, const float* v, const float* m, int g) {
    const size_t base = (size_t)(T_DIM - 1 - U * g) * B_DIM;
    #pragma unroll
    for (int j = 0; j < U; ++j) {
      const float d = fmaf(c_delta * m[j], v[j], r[j]);
      carry = fmaf(gl * m[j], carry, d);
      __builtin_nontemporal_store(carry, po + (base - (size_t)j * B_DIM));
    }
  };

  ld(rA, vA, mA, 0);
  ld(rB, vB, mB, 1);

  for (int g = 0; g < NGROUPS - 2; g += 2) {
    cmp(rA, vA, mA, g);         // waits on A (issued 2 groups ago)
    ld(rA, vA, mA, g + 2);      // refill A, overlaps B's compute
    cmp(rB, vB, mB, g + 1);
    if (g + 3 < NGROUPS) ld(rB, vB, mB, g + 3);
  }
  cmp(rA, vA, mA, NGROUPS - 2);
  cmp(rB, vB, mB, NGROUPS - 1);
}

extern "C" void kernel_launch(void* const* d_in, const int* in_sizes, int n_in,
                              void* d_out, int out_size, void* d_ws, size_t ws_size,
                              hipStream_t stream) {
  const float* rewards = (const float*)d_in[0];
  const float* values  = (const float*)d_in[1];
  const float* masks   = (const float*)d_in[2];
  float* out = (float*)d_out;

  dim3 grid(B_DIM / 64);
  dim3 block(64);
  LambdaReturn_kernel<<<grid, block, 0, stream>>>(rewards, values, masks, out);
}

// Round 3
// 351.742 us; speedup vs baseline: 1.0388x; 1.0111x over previous
//
#include <hip/hip_runtime.h>

// LambdaReturn: reverse-time linear recurrence, T=1000, B=32768, fp32.
//   delta_t = r_t + g*(1-l)*m_t*v_t ;  ret_t = delta_t + g*l*m_t*carry
//
// R1 result: U=10 dword pipeline materialized (VGPR=72) but dispatch stuck
// at 92 us profiled, hbm 3.5 TB/s (56% of achievable). Effective in-service
// bytes/CU ~5 KB despite 60-70 outstanding vmcnt ops -> request-COUNT
// limited (vmcnt slots / L1 request tracking), not byte-limited. Also
// 60 loads + 20 stores > 63 vmcnt cap -> intermittent issue stalls.
//
// R2: float2 per thread (one thread per column pair) -> container infra
// failure, no data. R3 = identical experiment, re-run.
// Every load/store is dwordx2 = 512 B/wave: same slot count, 2x bytes per
// slot. Carry chain splits into 2 independent FMA chains. Grid = 256
// blocks = 1 wave/CU (fine: latency hiding is ILP-based, VALUBusy was 10%).
// Prediction: VGPR ~140, profiled 92 -> 60-75 us if theory holds.

#define T_DIM 1000
#define B_DIM 32768
#define U 10          // timesteps per group; 1000 = 100 * 10
#define NGROUPS 100
#define ROW2 (B_DIM / 2)   // row stride in float2 units

typedef float v2f __attribute__((ext_vector_type(2)));

__global__ __launch_bounds__(64, 1) void LambdaReturn_kernel(
    const float* __restrict__ rewards,
    const float* __restrict__ values,
    const float* __restrict__ masks,
    float* __restrict__ out) {
  const int pair = blockIdx.x * blockDim.x + threadIdx.x;  // column pair id
  const float c_delta = 0.99f * (1.0f - 0.95f);  // gamma*(1-lambda)
  const float gl      = 0.99f * 0.95f;           // gamma*lambda

  const v2f* pr = (const v2f*)rewards + pair;
  const v2f* pv = (const v2f*)values + pair;
  const v2f* pm = (const v2f*)masks + pair;
  v2f* po = (v2f*)out + pair;

  v2f carry = pv[(size_t)(T_DIM - 1) * ROW2];

  v2f rA[U], vA[U], mA[U];
  v2f rB[U], vB[U], mB[U];

  // group g covers t = (999 - U*g) down to (999 - U*g - (U-1)), j = 0..U-1
  auto ld = [&](v2f* r, v2f* v, v2f* m, int g) {
    const size_t base = (size_t)(T_DIM - 1 - U * g) * ROW2;
    #pragma unroll
    for (int j = 0; j < U; ++j) {
      const size_t idx = base - (size_t)j * ROW2;
      r[j] = __builtin_nontemporal_load(pr + idx);
      v[j] = __builtin_nontemporal_load(pv + idx);
      m[j] = __builtin_nontemporal_load(pm + idx);
    }
    // Pin the issue point: scheduler may not sink these loads past here.
    // Waitcnt insertion is a later pass and still waits only at first use.
    __builtin_amdgcn_sched_barrier(0);
  };
  auto cmp = [&](const v2f* r, const v2f* v, const v2f* m, int g) {
    const size_t base = (size_t)(T_DIM - 1 - U * g) * ROW2;
    #pragma unroll
    for (int j = 0; j < U; ++j) {
      v2f d;
      d.x = __builtin_fmaf(c_delta * m[j].x, v[j].x, r[j].x);
      d.y = __builtin_fmaf(c_delta * m[j].y, v[j].y, r[j].y);
      carry.x = __builtin_fmaf(gl * m[j].x, carry.x, d.x);
      carry.y = __builtin_fmaf(gl * m[j].y, carry.y, d.y);
      __builtin_nontemporal_store(carry, po + (base - (size_t)j * ROW2));
    }
  };

  ld(rA, vA, mA, 0);
  ld(rB, vB, mB, 1);

  for (int g = 0; g < NGROUPS - 2; g += 2) {
    cmp(rA, vA, mA, g);         // waits on A (issued 2 groups ago)
    ld(rA, vA, mA, g + 2);      // refill A, overlaps B's compute
    cmp(rB, vB, mB, g + 1);
    if (g + 3 < NGROUPS) ld(rB, vB, mB, g + 3);
  }
  cmp(rA, vA, mA, NGROUPS - 2);
  cmp(rB, vB, mB, NGROUPS - 1);
}

extern "C" void kernel_launch(void* const* d_in, const int* in_sizes, int n_in,
                              void* d_out, int out_size, void* d_ws, size_t ws_size,
                              hipStream_t stream) {
  const float* rewards = (const float*)d_in[0];
  const float* values  = (const float*)d_in[1];
  const float* masks   = (const float*)d_in[2];
  float* out = (float*)d_out;

  dim3 grid(B_DIM / 2 / 64);   // 256 blocks = 1 wave64 per CU
  dim3 block(64);
  LambdaReturn_kernel<<<grid, block, 0, stream>>>(rewards, values, masks, out);
}

// Round 5
// 351.106 us; speedup vs baseline: 1.0406x; 1.0018x over previous
//
#include <hip/hip_runtime.h>

// LambdaReturn: reverse-time linear recurrence, T=1000, B=32768, fp32.
//   delta_t = r_t + g*(1-l)*m_t*v_t ;  ret_t = delta_t + g*l*m_t*carry
//
// History:
//  R1 scalar U=10 compiler-sched: 92 us, VGPR=72.
//  R3 float2 U=10, sched_barrier AFTER ld only: 90 us, VGPR=68 -> pipeline
//     collapsed: {cmp; ld} shared one sched region, scheduler interleaved
//     "load next[j]" right after "use cur[j]", RA reused registers ->
//     retire->issue serialization, ~25 loads in flight, 560ns loaded
//     latency => 22.7 GB/s/CU => 90 us. Latency-bound, not byte-bound
//     (hbm 3.6 TB/s = 45% peak; L3 reads 2.2 TB/s; neither at ceiling).
//  R4 per-instruction inline-asm pipeline: WRONG RESULTS — regalloc can
//     insert copies of asm-load dests before the hand-placed vmcnt
//     (sched_barrier doesn't fence regalloc). Never again at this
//     granularity; waitcnts stay with the compiler.
//
// R5: R3 + leading sched_barrier on every load block. Each ld is now a
// barrier-isolated region of ONLY loads: uses can't interleave with
// issues, so RA must keep both groups' 60 dwordx2 dests live (120 VGPRs)
// -> 60 loads / 30 KB genuinely in flight per wave (1 wave/CU; need
// ~15 KB for 6.3 TB/s). Compiler inserts exact counted vmcnt before each
// cmp's first use.
// Prediction: VGPR ~130-150. If latency-bound theory right: profiled
// 90 -> 60-80 us. If null at VGPR>=120: blended-path roofline, declare.

#define T_DIM 1000
#define B_DIM 32768
#define U 10          // timesteps per group; 1000 = 100 * 10
#define NGROUPS 100
#define ROW2 (B_DIM / 2)   // row stride in float2 units

typedef float v2f __attribute__((ext_vector_type(2)));

#define SBAR() __builtin_amdgcn_sched_barrier(0)

__global__ __launch_bounds__(64, 1) void LambdaReturn_kernel(
    const float* __restrict__ rewards,
    const float* __restrict__ values,
    const float* __restrict__ masks,
    float* __restrict__ out) {
  const int pair = blockIdx.x * blockDim.x + threadIdx.x;  // column pair id
  const float c_delta = 0.99f * (1.0f - 0.95f);  // gamma*(1-lambda)
  const float gl      = 0.99f * 0.95f;           // gamma*lambda

  const v2f* pr = (const v2f*)rewards + pair;
  const v2f* pv = (const v2f*)values + pair;
  const v2f* pm = (const v2f*)masks + pair;
  v2f* po = (v2f*)out + pair;

  v2f carry = pv[(size_t)(T_DIM - 1) * ROW2];

  v2f rA[U], vA[U], mA[U];
  v2f rB[U], vB[U], mB[U];

  // group g covers t = (999 - U*g) down to (999 - U*g - (U-1)), j = 0..U-1
  // Barrier-isolated: region contains ONLY these 30 loads. Leading SBAR
  // keeps the preceding cmp's uses out (that interleave is what enabled
  // register reuse and killed the pipeline in R3); trailing SBAR keeps
  // the following cmp's uses out.
  auto ld = [&](v2f* r, v2f* v, v2f* m, int g) {
    SBAR();
    const size_t base = (size_t)(T_DIM - 1 - U * g) * ROW2;
    #pragma unroll
    for (int j = 0; j < U; ++j) {
      const size_t idx = base - (size_t)j * ROW2;
      r[j] = __builtin_nontemporal_load(pr + idx);
      v[j] = __builtin_nontemporal_load(pv + idx);
      m[j] = __builtin_nontemporal_load(pm + idx);
    }
    SBAR();
  };
  auto cmp = [&](const v2f* r, const v2f* v, const v2f* m, int g) {
    const size_t base = (size_t)(T_DIM - 1 - U * g) * ROW2;
    #pragma unroll
    for (int j = 0; j < U; ++j) {
      v2f d;
      d.x = __builtin_fmaf(c_delta * m[j].x, v[j].x, r[j].x);
      d.y = __builtin_fmaf(c_delta * m[j].y, v[j].y, r[j].y);
      carry.x = __builtin_fmaf(gl * m[j].x, carry.x, d.x);
      carry.y = __builtin_fmaf(gl * m[j].y, carry.y, d.y);
      __builtin_nontemporal_store(carry, po + (base - (size_t)j * ROW2));
    }
  };

  ld(rA, vA, mA, 0);
  ld(rB, vB, mB, 1);

  for (int g = 0; g < NGROUPS - 2; g += 2) {
    cmp(rA, vA, mA, g);         // waits on A (issued 2 groups ago)
    ld(rA, vA, mA, g + 2);      // refill A, overlaps B's compute
    cmp(rB, vB, mB, g + 1);
    if (g + 3 < NGROUPS) ld(rB, vB, mB, g + 3);
  }
  cmp(rA, vA, mA, NGROUPS - 2);
  cmp(rB, vB, mB, NGROUPS - 1);
}

extern "C" void kernel_launch(void* const* d_in, const int* in_sizes, int n_in,
                              void* d_out, int out_size, void* d_ws, size_t ws_size,
                              hipStream_t stream) {
  const float* rewards = (const float*)d_in[0];
  const float* values  = (const float*)d_in[1];
  const float* masks   = (const float*)d_in[2];
  float* out = (float*)d_out;

  dim3 grid(B_DIM / 2 / 64);   // 256 blocks = 1 wave64 per CU
  dim3 block(64);
  LambdaReturn_kernel<<<grid, block, 0, stream>>>(rewards, values, masks, out);
}